// Round 8
// baseline (327.973 us; speedup 1.0000x reference)
//
#include <hip/hip_runtime.h>
#include <hip/hip_bf16.h>

#define D 128

typedef __attribute__((ext_vector_type(4))) float f32x4;
typedef __attribute__((ext_vector_type(8))) short bf16x8;

static __device__ __forceinline__ unsigned short f2bf(float f) {
    union { float f; unsigned int u; } v; v.f = f;
    unsigned int r = v.u + 0x7fffu + ((v.u >> 16) & 1u);
    return (unsigned short)(r >> 16);
}
static __device__ __forceinline__ float bf2f_lo(unsigned int v) {
    union { unsigned int u; float f; } x; x.u = v << 16; return x.f;
}
static __device__ __forceinline__ float bf2f_hi(unsigned int v) {
    union { unsigned int u; float f; } x; x.u = v & 0xffff0000u; return x.f;
}

// ---------------- packed: degree count + x->bf16 convert ------------------
__global__ __launch_bounds__(256) void deg_cvt_kernel(const int* __restrict__ dst,
                                                      int* __restrict__ deg, int E_,
                                                      const float* __restrict__ x,
                                                      unsigned short* __restrict__ xb,
                                                      int n4) {
    int bid = blockIdx.x;
    int ndeg = (E_ + 255) >> 8;
    if (bid < ndeg) {
        int e = bid * 256 + threadIdx.x;
        if (e < E_) atomicAdd(&deg[dst[e]], 1);
    } else {
        int i = (bid - ndeg) * 256 + threadIdx.x;
        if (i < n4) {
            float4 v = reinterpret_cast<const float4*>(x)[i];
            ushort4 o;
            o.x = f2bf(v.x); o.y = f2bf(v.y); o.z = f2bf(v.z); o.w = f2bf(v.w);
            reinterpret_cast<ushort4*>(xb)[i] = o;
        }
    }
}

// ---------------- single-block parallel scan (1024 thr, ~40 nodes/thr) ----
__global__ __launch_bounds__(1024) void scan_one_kernel(const int* __restrict__ deg,
                                                        int* __restrict__ row_start,
                                                        int* __restrict__ cursor,
                                                        int N_, int E_) {
    const int T = 1024;
    int tid = threadIdx.x;
    int C = (N_ + T - 1) / T;
    int beg = tid * C;
    int end = beg + C;
    if (end > N_) end = N_;
    if (beg > N_) beg = N_;

    int local = 0;
    for (int i = beg; i < end; ++i) local += deg[i];

    int lane = tid & 63, wid = tid >> 6;
    int inc = local;
#pragma unroll
    for (int off = 1; off < 64; off <<= 1) {
        int n = __shfl_up(inc, off, 64);
        if (lane >= off) inc += n;
    }
    __shared__ int wsum[16];
    if (lane == 63) wsum[wid] = inc;
    __syncthreads();
    int wofs = 0;
    for (int w = 0; w < wid; ++w) wofs += wsum[w];
    int run = wofs + inc - local;  // exclusive prefix of this thread's chunk

    for (int i = beg; i < end; ++i) {
        row_start[i] = run;
        cursor[i] = run;
        run += deg[i];
    }
    if (tid == 0) row_start[N_] = E_;
}

// ---------------- packed: CSR placement + W^T prep (3 layers) -------------
__global__ __launch_bounds__(256) void place_wt_kernel(
    const int* __restrict__ src, const int* __restrict__ dst,
    int* __restrict__ cursor, int* __restrict__ csr_src, int E_,
    const float* __restrict__ Wl0, const float* __restrict__ Wr0,
    const float* __restrict__ Wl1, const float* __restrict__ Wr1,
    const float* __restrict__ Wl2, const float* __restrict__ Wr2,
    unsigned short* __restrict__ WtB) {
    int bid = blockIdx.x;
    int nplace = (E_ + 255) >> 8;
    if (bid < nplace) {
        int e = bid * 256 + threadIdx.x;
        if (e < E_) {
            int pos = atomicAdd(&cursor[dst[e]], 1);
            csr_src[pos] = src[e];
        }
        return;
    }
    int idx = bid - nplace;              // 0..47
    int layer = idx >> 4;
    int j = (idx & 15) * 256 + threadIdx.x;  // 0..4095
    const float* Wl = (layer == 0) ? Wl0 : (layer == 1) ? Wl1 : Wl2;
    const float* Wr = (layer == 0) ? Wr0 : (layer == 1) ? Wr1 : Wr2;
    unsigned short* Wt = WtB + (size_t)layer * 128 * 256;
    int c = j >> 5;
    int g = j & 31;
    int k0 = g * 8;
    const float* Wsrc = (k0 < 128) ? (Wl + (size_t)k0 * D + c)
                                   : (Wr + (size_t)(k0 - 128) * D + c);
    float v[8];
#pragma unroll
    for (int i = 0; i < 8; ++i) v[i] = Wsrc[(size_t)i * D];
    uint4 o;
    o.x = (unsigned int)f2bf(v[0]) | ((unsigned int)f2bf(v[1]) << 16);
    o.y = (unsigned int)f2bf(v[2]) | ((unsigned int)f2bf(v[3]) << 16);
    o.z = (unsigned int)f2bf(v[4]) | ((unsigned int)f2bf(v[5]) << 16);
    o.w = (unsigned int)f2bf(v[6]) | ((unsigned int)f2bf(v[7]) << 16);
    *reinterpret_cast<uint4*>(Wt + (size_t)c * 256 + k0) = o;
}

// ---------------- fused layer: gather-mean (LDS) + MFMA GEMM --------------
// 512 thr = 8 waves, 128 rows/block (16/wave). K=256 in two halves:
//   sWtA = W^T k 0..127 (agg half); sBuf = agg tile, then W^T k 128..255.
// Each wave gathers agg for ITS 16 MFMA rows -> no cross-wave dependency.
// hin A-frags loaded to registers at kernel entry (latency hidden by gather).
// MODE 0: bf16 out + relu; MODE 1: f32 out, no relu.
template <int MODE>
__global__ __launch_bounds__(512) void sage_layer_fused(
    const unsigned short* __restrict__ hinb, const int* __restrict__ row_start,
    const int* __restrict__ csr_src, const unsigned short* __restrict__ WtB,
    const float* __restrict__ bias, void* __restrict__ out, int N_) {
    __shared__ unsigned short sWtA[128][136];  // [col][k 0..127], +8 pad
    __shared__ unsigned short sBuf[128][136];  // agg tile -> W^T half 2

    const int tid = threadIdx.x;
    const int lane = tid & 63;
    const int w = tid >> 6;       // wave 0..7
    const int q = lane >> 4;      // 0..3
    const int t = lane & 15;      // 0..15
    const int node0 = blockIdx.x * 128 + w * 16;

    // hin A-fragments for K-half 2 (cols 0..127 of hin): issue immediately
    int r0 = node0 + t; if (r0 > N_ - 1) r0 = N_ - 1;
    bf16x8 a_hin[4];
#pragma unroll
    for (int ks = 0; ks < 4; ++ks)
        a_hin[ks] = *reinterpret_cast<const bf16x8*>(hinb + (size_t)r0 * D + ks * 32 + q * 8);

    // stage W^T half 1 (k 0..127): 2048 uint4 chunks / 512 thr
    for (int idx = tid; idx < 128 * 16; idx += 512) {
        int cc = idx >> 4, g = idx & 15;
        *reinterpret_cast<uint4*>(&sWtA[cc][g * 8]) =
            reinterpret_cast<const uint4*>(WtB + (size_t)cc * 256)[g];
    }

    // ---- phase 1: gather-mean for this wave's 16 rows into sBuf ----
    int rsv = row_start[min(node0 + (int)lane, N_)];
    const uint4* hb4 = reinterpret_cast<const uint4*>(hinb);  // row = 16 uint4

#define ACC8(V)                                             \
    acc[0] += bf2f_lo(V.x); acc[1] += bf2f_hi(V.x);         \
    acc[2] += bf2f_lo(V.y); acc[3] += bf2f_hi(V.y);         \
    acc[4] += bf2f_lo(V.z); acc[5] += bf2f_hi(V.z);         \
    acc[6] += bf2f_lo(V.w); acc[7] += bf2f_hi(V.w);

    for (int i = 0; i < 16; ++i) {
        int node = node0 + i;
        if (node >= N_) break;
        int beg = __shfl(rsv, i, 64);
        int end = __shfl(rsv, i + 1, 64);
        float acc[8];
#pragma unroll
        for (int j = 0; j < 8; ++j) acc[j] = 0.f;

        int e = beg + q;
        for (; e + 12 < end; e += 16) {
            int s0 = csr_src[e];
            int s1 = csr_src[e + 4];
            int s2 = csr_src[e + 8];
            int s3 = csr_src[e + 12];
            uint4 v0 = hb4[(size_t)s0 * 16 + t];
            uint4 v1 = hb4[(size_t)s1 * 16 + t];
            uint4 v2 = hb4[(size_t)s2 * 16 + t];
            uint4 v3 = hb4[(size_t)s3 * 16 + t];
            ACC8(v0); ACC8(v1); ACC8(v2); ACC8(v3);
        }
        for (; e < end; e += 4) {
            uint4 v0 = hb4[(size_t)csr_src[e] * 16 + t];
            ACC8(v0);
        }
        // cross-quarter reduce (quarters at lane offsets 16)
#pragma unroll
        for (int j = 0; j < 8; ++j) {
            acc[j] += __shfl_xor(acc[j], 16, 64);
            acc[j] += __shfl_xor(acc[j], 32, 64);
        }
        if (q == 0) {
            int dgr = end - beg;
            float sc = 1.0f / (float)(dgr > 0 ? dgr : 1);
            uint4 o;
            o.x = (unsigned int)f2bf(acc[0] * sc) | ((unsigned int)f2bf(acc[1] * sc) << 16);
            o.y = (unsigned int)f2bf(acc[2] * sc) | ((unsigned int)f2bf(acc[3] * sc) << 16);
            o.z = (unsigned int)f2bf(acc[4] * sc) | ((unsigned int)f2bf(acc[5] * sc) << 16);
            o.w = (unsigned int)f2bf(acc[6] * sc) | ((unsigned int)f2bf(acc[7] * sc) << 16);
            *reinterpret_cast<uint4*>(&sBuf[w * 16 + i][t * 8]) = o;
        }
    }
#undef ACC8
    __syncthreads();  // sWtA staged by all; sBuf agg rows are wave-local

    // ---- phase 2a: K-half 1 — A = agg (LDS), B = sWtA ----
    f32x4 acc2[8];
#pragma unroll
    for (int n = 0; n < 8; ++n) acc2[n] = (f32x4){0.f, 0.f, 0.f, 0.f};

#pragma unroll
    for (int ks = 0; ks < 4; ++ks) {
        bf16x8 a0 = *reinterpret_cast<const bf16x8*>(&sBuf[w * 16 + t][ks * 32 + q * 8]);
#pragma unroll
        for (int n = 0; n < 8; ++n) {
            bf16x8 b = *reinterpret_cast<const bf16x8*>(&sWtA[n * 16 + t][ks * 32 + q * 8]);
            acc2[n] = __builtin_amdgcn_mfma_f32_16x16x32_bf16(a0, b, acc2[n], 0, 0, 0);
        }
    }
    __syncthreads();  // agg consumed; reuse sBuf for W^T half 2

    for (int idx = tid; idx < 128 * 16; idx += 512) {
        int cc = idx >> 4, g = idx & 15;
        *reinterpret_cast<uint4*>(&sBuf[cc][g * 8]) =
            reinterpret_cast<const uint4*>(WtB + (size_t)cc * 256 + 128)[g];
    }
    __syncthreads();

    // ---- phase 2b: K-half 2 — A = hin (registers), B = sBuf ----
#pragma unroll
    for (int ks = 0; ks < 4; ++ks) {
#pragma unroll
        for (int n = 0; n < 8; ++n) {
            bf16x8 b = *reinterpret_cast<const bf16x8*>(&sBuf[n * 16 + t][ks * 32 + q * 8]);
            acc2[n] = __builtin_amdgcn_mfma_f32_16x16x32_bf16(a_hin[ks], b, acc2[n], 0, 0, 0);
        }
    }

    // epilogue: C row=(q*4+r), col=t within each 16x16 frag  [m89-verified]
    unsigned short* outb = (unsigned short*)out;
    float* outf = (float*)out;
#pragma unroll
    for (int n = 0; n < 8; ++n) {
        int col = n * 16 + t;
        float bv = bias[col];
#pragma unroll
        for (int r = 0; r < 4; ++r) {
            int row = node0 + q * 4 + r;
            if (row < N_) {
                float v = acc2[n][r] + bv;
                if (MODE == 0) {
                    v = fmaxf(v, 0.f);
                    outb[(size_t)row * D + col] = f2bf(v);
                } else {
                    outf[(size_t)row * D + col] = v;
                }
            }
        }
    }
}

extern "C" void kernel_launch(void* const* d_in, const int* in_sizes, int n_in,
                              void* d_out, int out_size, void* d_ws, size_t ws_size,
                              hipStream_t stream) {
    const float* x = (const float*)d_in[0];
    const int* edge = (const int*)d_in[1];
    const float* Wl[3] = {(const float*)d_in[2], (const float*)d_in[5], (const float*)d_in[8]};
    const float* Wr[3] = {(const float*)d_in[3], (const float*)d_in[6], (const float*)d_in[9]};
    const float* bs[3] = {(const float*)d_in[4], (const float*)d_in[7], (const float*)d_in[10]};

    const int N_ = in_sizes[0] / D;
    const int E_ = in_sizes[1] / 2;
    const int* src = edge;
    const int* dst = edge + E_;

    char* ws = (char*)d_ws;
    size_t bmat = (size_t)N_ * D * sizeof(unsigned short);  // 10.24 MB
    unsigned short* xb = (unsigned short*)ws;                // also reused as h2b
    unsigned short* h1b = (unsigned short*)(ws + bmat);
    char* p = ws + 2 * bmat;
    int* deg_i = (int*)p;       p += (size_t)N_ * 4;
    int* row_start = (int*)p;   p += (size_t)(N_ + 1) * 4;
    int* cursor = (int*)p;      p += (size_t)N_ * 4;
    unsigned short* WtB = (unsigned short*)p; p += 3 * 128 * 256 * sizeof(unsigned short);
    int* csr_src = (int*)p;     p += (size_t)E_ * 4;

    const int ndeg = (E_ + 255) / 256;    // 2500
    const int n4 = N_ * D / 4;
    const int ncvt = (n4 + 255) / 256;    // 5000

    // ---- CSR build + input convert (7 dispatches total this launch) ----
    hipMemsetAsync(deg_i, 0, (size_t)N_ * sizeof(int), stream);
    deg_cvt_kernel<<<ndeg + ncvt, 256, 0, stream>>>(dst, deg_i, E_, x, xb, n4);
    scan_one_kernel<<<1, 1024, 0, stream>>>(deg_i, row_start, cursor, N_, E_);
    place_wt_kernel<<<ndeg + 48, 256, 0, stream>>>(src, dst, cursor, csr_src, E_,
                                                   Wl[0], Wr[0], Wl[1], Wr[1], Wl[2], Wr[2], WtB);

    int blocks = (N_ + 127) / 128;
    unsigned short* h2b = xb;  // x dead after layer 0

    sage_layer_fused<0><<<blocks, 512, 0, stream>>>(xb, row_start, csr_src,
                                                    WtB, bs[0], h1b, N_);
    sage_layer_fused<0><<<blocks, 512, 0, stream>>>(h1b, row_start, csr_src,
                                                    WtB + 128 * 256, bs[1], h2b, N_);
    sage_layer_fused<1><<<blocks, 512, 0, stream>>>(h2b, row_start, csr_src,
                                                    WtB + 2 * 128 * 256, bs[2], d_out, N_);
}